// Round 8
// baseline (217.065 us; speedup 1.0000x reference)
//
#include <hip/hip_runtime.h>
#include <hip/hip_bf16.h>
#include <hip/hip_fp16.h>
#include <math.h>

#define V 2048
#define C 64
#define NB 8
#define M_TOTAL (NB * V)   // 16384 rows total

typedef __attribute__((ext_vector_type(8))) short bf16x8;
typedef __attribute__((ext_vector_type(4))) float f32x4;
typedef __attribute__((ext_vector_type(16))) float f32x16;

static __device__ __forceinline__ unsigned short f2bf(float f) {
    __hip_bfloat16 h = __float2bfloat16(f);   // RNE
    return *reinterpret_cast<unsigned short*>(&h);
}
static __device__ __forceinline__ unsigned short f2h(float f) {
    __half h = __float2half(f);
    return *reinterpret_cast<unsigned short*>(&h);
}
static __device__ __forceinline__ float h2f(unsigned short u) {
    __half h = *reinterpret_cast<__half*>(&u);
    return __half2float(h);
}

#define GLOAD_LDS16(g, l)                                                        \
    __builtin_amdgcn_global_load_lds((const __attribute__((address_space(1))) void*)(g), \
                                     (__attribute__((address_space(3))) void*)(l), 16, 0, 0)

// ============================ FAST PATH (needs d_ws) ============================

// ---- adj via MFMA gram: adjb[n*V+i][j] = bf16(exp(-0.5*sqrt(qi+qj-2*G_ij))) ----
// q computed IN-BLOCK with the bit-identical MFMA chain on the same LDS bf16
// data, so diagonal d^2 == 0 exactly.
__global__ __launch_bounds__(256) void adj_mfma(const float* __restrict__ x,
                                                unsigned short* __restrict__ adjb) {
    const int n  = blockIdx.z;
    const int i0 = blockIdx.y * 128;
    const int j0 = blockIdx.x * 128;
    const size_t nV = (size_t)n * V;

    __shared__ short Xi[128][72];
    __shared__ short Xj[128][72];
    __shared__ float Qi[128];
    __shared__ float Qj[128];

    const float* xn = x + nV * C;
    const int tid = threadIdx.x;

    for (int idx = tid; idx < 1024; idx += 256) {
        const int row = idx >> 3;
        const int c8  = (idx & 7) * 8;
        float4 ai0 = *(const float4*)(xn + (size_t)(i0 + row) * C + c8);
        float4 ai1 = *(const float4*)(xn + (size_t)(i0 + row) * C + c8 + 4);
        float4 aj0 = *(const float4*)(xn + (size_t)(j0 + row) * C + c8);
        float4 aj1 = *(const float4*)(xn + (size_t)(j0 + row) * C + c8 + 4);
        bf16x8 pi, pj;
        pi[0] = (short)f2bf(ai0.x); pi[1] = (short)f2bf(ai0.y);
        pi[2] = (short)f2bf(ai0.z); pi[3] = (short)f2bf(ai0.w);
        pi[4] = (short)f2bf(ai1.x); pi[5] = (short)f2bf(ai1.y);
        pi[6] = (short)f2bf(ai1.z); pi[7] = (short)f2bf(ai1.w);
        pj[0] = (short)f2bf(aj0.x); pj[1] = (short)f2bf(aj0.y);
        pj[2] = (short)f2bf(aj0.z); pj[3] = (short)f2bf(aj0.w);
        pj[4] = (short)f2bf(aj1.x); pj[5] = (short)f2bf(aj1.y);
        pj[6] = (short)f2bf(aj1.z); pj[7] = (short)f2bf(aj1.w);
        *(bf16x8*)&Xi[row][c8] = pi;
        *(bf16x8*)&Xj[row][c8] = pj;
    }
    __syncthreads();

    const int wid  = tid >> 6;
    const int lane = tid & 63;
    const int wr = wid >> 1, wc = wid & 1;
    const int lr = lane & 15, lq = lane >> 4;

    // ---- in-block q (same chain as gram below) ----
#pragma unroll
    for (int gg = 0; gg < 2; ++gg) {
        const int g = wid * 2 + gg;             // 0..7
        {
            const short* xr = &Xi[g * 16 + lr][0];
            bf16x8 a0 = *(const bf16x8*)(xr + lq * 8);
            bf16x8 a1 = *(const bf16x8*)(xr + 32 + lq * 8);
            f32x4 qa = (f32x4){0.f, 0.f, 0.f, 0.f};
            qa = __builtin_amdgcn_mfma_f32_16x16x32_bf16(a0, a0, qa, 0, 0, 0);
            qa = __builtin_amdgcn_mfma_f32_16x16x32_bf16(a1, a1, qa, 0, 0, 0);
            if (lq == (lr >> 2)) Qi[g * 16 + lr] = qa[lr & 3];
        }
        {
            const short* xr = &Xj[g * 16 + lr][0];
            bf16x8 a0 = *(const bf16x8*)(xr + lq * 8);
            bf16x8 a1 = *(const bf16x8*)(xr + 32 + lq * 8);
            f32x4 qa = (f32x4){0.f, 0.f, 0.f, 0.f};
            qa = __builtin_amdgcn_mfma_f32_16x16x32_bf16(a0, a0, qa, 0, 0, 0);
            qa = __builtin_amdgcn_mfma_f32_16x16x32_bf16(a1, a1, qa, 0, 0, 0);
            if (lq == (lr >> 2)) Qj[g * 16 + lr] = qa[lr & 3];
        }
    }
    __syncthreads();

    bf16x8 a[4][2], b[4][2];
#pragma unroll
    for (int m = 0; m < 4; ++m) {
        a[m][0] = *(const bf16x8*)&Xi[wr * 64 + m * 16 + lr][lq * 8];
        a[m][1] = *(const bf16x8*)&Xi[wr * 64 + m * 16 + lr][32 + lq * 8];
    }
#pragma unroll
    for (int nn = 0; nn < 4; ++nn) {
        b[nn][0] = *(const bf16x8*)&Xj[wc * 64 + nn * 16 + lr][lq * 8];
        b[nn][1] = *(const bf16x8*)&Xj[wc * 64 + nn * 16 + lr][32 + lq * 8];
    }

#pragma unroll
    for (int m = 0; m < 4; ++m) {
#pragma unroll
        for (int nn = 0; nn < 4; ++nn) {
            f32x4 g = (f32x4){0.f, 0.f, 0.f, 0.f};
            g = __builtin_amdgcn_mfma_f32_16x16x32_bf16(a[m][0], b[nn][0], g, 0, 0, 0);
            g = __builtin_amdgcn_mfma_f32_16x16x32_bf16(a[m][1], b[nn][1], g, 0, 0, 0);
            const int col_l = wc * 64 + nn * 16 + lr;
            const float qj = Qj[col_l];
#pragma unroll
            for (int r = 0; r < 4; ++r) {
                const int row_l = wr * 64 + m * 16 + lq * 4 + r;
                float d2 = Qi[row_l] + qj - 2.0f * g[r];
                d2 = fmaxf(d2, 0.0f);
                const float e = __expf(-0.5f * sqrtf(d2));
                adjb[(nV + i0 + row_l) * V + j0 + col_l] = f2bf(e);
            }
        }
    }
}

// ---- W transpose to bf16 ----
__global__ __launch_bounds__(256) void wt_kernel(const float* __restrict__ w,
                                                 unsigned short* __restrict__ wt) {
    __shared__ float tile[64][65];
    const int r0 = blockIdx.y * 64, c0 = blockIdx.x * 64;
    const int tr = threadIdx.x >> 4;
    const int tc4 = (threadIdx.x & 15) << 2;
#pragma unroll
    for (int it = 0; it < 4; ++it) {
        const int r = tr + 16 * it;
        float4 v = *(const float4*)(w + (size_t)(r0 + r) * V + c0 + tc4);
        tile[r][tc4 + 0] = v.x; tile[r][tc4 + 1] = v.y;
        tile[r][tc4 + 2] = v.z; tile[r][tc4 + 3] = v.w;
    }
    __syncthreads();
#pragma unroll
    for (int it = 0; it < 4; ++it) {
        const int cr = tr + 16 * it;
        ushort4 o;
        o.x = f2bf(tile[tc4 + 0][cr]);
        o.y = f2bf(tile[tc4 + 1][cr]);
        o.z = f2bf(tile[tc4 + 2][cr]);
        o.w = f2bf(tile[tc4 + 3][cr]);
        *(ushort4*)(wt + (size_t)(c0 + cr) * V + r0 + tc4) = o;
    }
}

// ============== 256x256 8-phase MFMA GEMM, 32x32x16 fragments ==============
// Same proven T2+T3+T4+T5 schedule as rounds 4-6; MFMA shape switched to
// 32x32x16 (2382 vs 2075 TF ubench, half the issue slots). Per phase:
// 2m x 2n x 2k16 = 8 MFMA. A/B lane map: row=lane&31, k=(lane>>5)*8.
// C/D map: col=lane&31, row=(reg&3)+8*(reg>>2)+4*(lane>>5)  [m74/m101].
__device__ __forceinline__ void stage_region(char* smem, int regionOff,
                                             const unsigned short* gbase,
                                             int tile, int ks, int tid) {
#pragma unroll
    for (int s = 0; s < 2; ++s) {
        const int off = s * 8192 + tid * 16;       // linear LDS byte offset
        const int row = off >> 6;
        const int pb  = off & 63;
        const int lb  = pb ^ (((row >> 1) & 3) << 4);  // inverse swizzle on source
        const unsigned short* g = gbase + (size_t)row * V + tile * 64 + ks * 32 + (lb >> 1);
        GLOAD_LDS16(g, smem + regionOff + off);
    }
}

#define LDS_FRAG32(BUF, BOFF, KS, KB, ROW)                                       \
    (*(const bf16x8*)(smem + (BUF) * 65536 + (BOFF) + (KS) * 16384 +             \
                      (ROW) * 64 + ((((KB) * 32) + lkb) ^ ((((ROW) >> 1) & 3) << 4))))

#define PHASE32(BUF, MH, KS, LOADB, STAGE_STMT, WAITV)                           \
    {                                                                            \
        bf16x8 af00 = LDS_FRAG32(BUF, 0, KS, 0, wr128 + ((MH) * 2 + 0) * 32 + l31); \
        bf16x8 af01 = LDS_FRAG32(BUF, 0, KS, 1, wr128 + ((MH) * 2 + 0) * 32 + l31); \
        bf16x8 af10 = LDS_FRAG32(BUF, 0, KS, 0, wr128 + ((MH) * 2 + 1) * 32 + l31); \
        bf16x8 af11 = LDS_FRAG32(BUF, 0, KS, 1, wr128 + ((MH) * 2 + 1) * 32 + l31); \
        if (LOADB) {                                                             \
            bf[0][0] = LDS_FRAG32(BUF, 32768, KS, 0, wc64 + l31);                \
            bf[0][1] = LDS_FRAG32(BUF, 32768, KS, 1, wc64 + l31);                \
            bf[1][0] = LDS_FRAG32(BUF, 32768, KS, 0, wc64 + 32 + l31);           \
            bf[1][1] = LDS_FRAG32(BUF, 32768, KS, 1, wc64 + 32 + l31);           \
        }                                                                        \
        STAGE_STMT;                                                              \
        if (WAITV) {                                                             \
            asm volatile("s_waitcnt vmcnt(6)" ::: "memory");                     \
            __builtin_amdgcn_sched_barrier(0);                                   \
        }                                                                        \
        __builtin_amdgcn_s_barrier();                                            \
        asm volatile("s_waitcnt lgkmcnt(0)" ::: "memory");                       \
        __builtin_amdgcn_sched_barrier(0);                                       \
        __builtin_amdgcn_s_setprio(1);                                           \
        acc32[(MH) * 2 + 0][0] = __builtin_amdgcn_mfma_f32_32x32x16_bf16(af00, bf[0][0], acc32[(MH) * 2 + 0][0], 0, 0, 0); \
        acc32[(MH) * 2 + 0][0] = __builtin_amdgcn_mfma_f32_32x32x16_bf16(af01, bf[0][1], acc32[(MH) * 2 + 0][0], 0, 0, 0); \
        acc32[(MH) * 2 + 0][1] = __builtin_amdgcn_mfma_f32_32x32x16_bf16(af00, bf[1][0], acc32[(MH) * 2 + 0][1], 0, 0, 0); \
        acc32[(MH) * 2 + 0][1] = __builtin_amdgcn_mfma_f32_32x32x16_bf16(af01, bf[1][1], acc32[(MH) * 2 + 0][1], 0, 0, 0); \
        acc32[(MH) * 2 + 1][0] = __builtin_amdgcn_mfma_f32_32x32x16_bf16(af10, bf[0][0], acc32[(MH) * 2 + 1][0], 0, 0, 0); \
        acc32[(MH) * 2 + 1][0] = __builtin_amdgcn_mfma_f32_32x32x16_bf16(af11, bf[0][1], acc32[(MH) * 2 + 1][0], 0, 0, 0); \
        acc32[(MH) * 2 + 1][1] = __builtin_amdgcn_mfma_f32_32x32x16_bf16(af10, bf[1][0], acc32[(MH) * 2 + 1][1], 0, 0, 0); \
        acc32[(MH) * 2 + 1][1] = __builtin_amdgcn_mfma_f32_32x32x16_bf16(af11, bf[1][1], acc32[(MH) * 2 + 1][1], 0, 0, 0); \
        __builtin_amdgcn_s_setprio(0);                                           \
        __builtin_amdgcn_s_barrier();                                            \
    }

template <int FUSED>
__global__ __launch_bounds__(512, 2) void gemm_8ph(const unsigned short* __restrict__ adjb,
                                                   const unsigned short* __restrict__ wtb,
                                                   float* __restrict__ out,
                                                   unsigned short* __restrict__ expw) {
    extern __shared__ char smem[];

    const int bid = blockIdx.x;
    const int swz = (bid & 7) * 64 + (bid >> 3);   // bijective XCD swizzle (512%8==0)
    const int by = swz >> 3;            // 0..63
    const int bx = swz & 7;             // 0..7
    const int i0 = by * 256;
    const int n0 = bx * 256;

    const int tid  = threadIdx.x;
    const int wid  = tid >> 6;
    const int lane = tid & 63;
    const int wr = wid >> 2, wc = wid & 3;        // 2 x 4 waves
    const int wr128 = wr * 128, wc64 = wc * 64;
    const int l31 = lane & 31, l5 = lane >> 5;
    const int lkb = l5 * 16;

    const unsigned short* gA = adjb + (size_t)i0 * V;
    const unsigned short* gB = wtb  + (size_t)n0 * V;

    f32x16 acc32[4][2];
#pragma unroll
    for (int m = 0; m < 4; ++m)
#pragma unroll
        for (int n = 0; n < 2; ++n)
#pragma unroll
            for (int g = 0; g < 16; ++g) acc32[m][n][g] = 0.f;

    // prologue: buf0 <- tile0 (4 regions), buf1 <- tile1 (Bk0,Ak0,Bk1)
    stage_region(smem, 32768,         gB, 0, 0, tid);
    stage_region(smem, 0,             gA, 0, 0, tid);
    stage_region(smem, 49152,         gB, 0, 1, tid);
    stage_region(smem, 16384,         gA, 0, 1, tid);
    stage_region(smem, 65536 + 32768, gB, 1, 0, tid);
    stage_region(smem, 65536 + 0,     gA, 1, 0, tid);
    stage_region(smem, 65536 + 49152, gB, 1, 1, tid);
    asm volatile("s_waitcnt vmcnt(6)" ::: "memory");
    __builtin_amdgcn_sched_barrier(0);
    __builtin_amdgcn_s_barrier();

    bf16x8 bf[2][2];

#pragma unroll 1
    for (int i = 0; i < 16; ++i) {
        const int t1b = 2 * i + 1;
        const int t2  = (2 * i + 2 < 32) ? 2 * i + 2 : 31;   // clamp: idempotent tail
        const int t3  = (2 * i + 3 < 32) ? 2 * i + 3 : 31;

        PHASE32(0, 0, 0, true,  stage_region(smem, 65536 + 16384, gA, t1b, 1, tid), false)
        PHASE32(0, 1, 0, false, stage_region(smem, 32768,         gB, t2,  0, tid), false)
        PHASE32(0, 0, 1, true,  stage_region(smem, 0,             gA, t2,  0, tid), false)
        PHASE32(0, 1, 1, false, stage_region(smem, 49152,         gB, t2,  1, tid), true)
        PHASE32(1, 0, 0, true,  stage_region(smem, 16384,         gA, t2,  1, tid), false)
        PHASE32(1, 1, 0, false, stage_region(smem, 65536 + 32768, gB, t3,  0, tid), false)
        PHASE32(1, 0, 1, true,  stage_region(smem, 65536 + 0,     gA, t3,  0, tid), false)
        PHASE32(1, 1, 1, false, stage_region(smem, 65536 + 49152, gB, t3,  1, tid), true)
    }

    // C/D 32x32 map: col = lane&31, row = (reg&3) + 8*(reg>>2) + 4*(lane>>5)
    if (FUSED) {
        unsigned short* ep = expw + (size_t)(i0 + wr128) * V + n0 + wc64;
#pragma unroll
        for (int m = 0; m < 4; ++m)
#pragma unroll
            for (int g = 0; g < 16; ++g) {
                const int row = m * 32 + (g & 3) + 8 * (g >> 2) + 4 * l5;
#pragma unroll
                for (int n = 0; n < 2; ++n)
                    ep[(size_t)row * V + n * 32 + l31] = f2h(__expf(acc32[m][n][g]));
            }
    } else {
        float* op = out + (size_t)(i0 + wr128) * V + n0 + wc64;
#pragma unroll
        for (int m = 0; m < 4; ++m)
#pragma unroll
            for (int g = 0; g < 16; ++g) {
                const int row = m * 32 + (g & 3) + 8 * (g >> 2) + 4 * l5;
#pragma unroll
                for (int n = 0; n < 2; ++n)
                    op[(size_t)row * V + n * 32 + l31] = acc32[m][n][g];
            }
    }
}

// ---- softmax stage 2: single pass — sum fp16 exp row, scale, write fp32 (nt) ----
__global__ __launch_bounds__(256) void normalize_kernel(const unsigned short* __restrict__ expw,
                                                        float* __restrict__ out) {
    const int row  = blockIdx.x * 4 + (threadIdx.x >> 6);
    const int lane = threadIdx.x & 63;

    const unsigned short* ip = expw + (size_t)row * V;
    float* op = out + (size_t)row * V;

    float v[32];
    float sum = 0.0f;
#pragma unroll
    for (int t = 0; t < 4; ++t) {
        const int base = (t * 64 + lane) * 8;
        ushort4 u0 = *(const ushort4*)(ip + base);
        ushort4 u1 = *(const ushort4*)(ip + base + 4);
        v[t * 8 + 0] = h2f(u0.x); v[t * 8 + 1] = h2f(u0.y);
        v[t * 8 + 2] = h2f(u0.z); v[t * 8 + 3] = h2f(u0.w);
        v[t * 8 + 4] = h2f(u1.x); v[t * 8 + 5] = h2f(u1.y);
        v[t * 8 + 6] = h2f(u1.z); v[t * 8 + 7] = h2f(u1.w);
#pragma unroll
        for (int k = 0; k < 8; ++k) sum += v[t * 8 + k];
    }
#pragma unroll
    for (int o = 32; o; o >>= 1) sum += __shfl_xor(sum, o);
    const float inv = 1.0f / sum;

#pragma unroll
    for (int t = 0; t < 4; ++t) {
        const int base = (t * 64 + lane) * 8;
        f32x4 o0, o1;
        o0[0] = v[t * 8 + 0] * inv; o0[1] = v[t * 8 + 1] * inv;
        o0[2] = v[t * 8 + 2] * inv; o0[3] = v[t * 8 + 3] * inv;
        o1[0] = v[t * 8 + 4] * inv; o1[1] = v[t * 8 + 5] * inv;
        o1[2] = v[t * 8 + 6] * inv; o1[3] = v[t * 8 + 7] * inv;
        __builtin_nontemporal_store(o0, (f32x4*)(op + base));
        __builtin_nontemporal_store(o1, (f32x4*)(op + base + 4));
    }
}

// ---- backup MFMA GEMM (proven round-3 kernel) ----
__global__ __launch_bounds__(256) void gemm_mfma(const unsigned short* __restrict__ adjb,
                                                 const unsigned short* __restrict__ wtb,
                                                 float* __restrict__ out) {
    const int bid = blockIdx.x;
    const int swz = (bid & 7) * 256 + (bid >> 3);
    const int by = swz >> 4;
    const int bx = swz & 15;
    const int i0 = by * 128;
    const int n0 = bx * 128;

    __shared__ alignas(16) unsigned short As[128 * 32];
    __shared__ alignas(16) unsigned short Bs[128 * 32];

    const int tid  = threadIdx.x;
    const int wid  = tid >> 6;
    const int lane = tid & 63;
    const int wr = wid >> 1, wc = wid & 1;
    const int lr = lane & 15, lq = lane >> 4;

    f32x4 acc[4][4];
#pragma unroll
    for (int m = 0; m < 4; ++m)
#pragma unroll
        for (int n = 0; n < 4; ++n) acc[m][n] = (f32x4){0.f, 0.f, 0.f, 0.f};

    const unsigned short* ga = adjb + (size_t)(i0 + (tid >> 2)) * V + (tid & 3) * 8;
    const unsigned short* gb = wtb  + (size_t)(n0 + (tid >> 2)) * V + (tid & 3) * 8;
    unsigned short* lA = &As[tid * 8];
    unsigned short* lB = &Bs[tid * 8];
    const size_t rowskip = (size_t)64 * V;

    for (int kt = 0; kt < 64; ++kt) {
        const int k0 = kt * 32;
        if (kt) __syncthreads();
        GLOAD_LDS16(ga + k0,           lA);
        GLOAD_LDS16(ga + rowskip + k0, lA + 256 * 8);
        GLOAD_LDS16(gb + k0,           lB);
        GLOAD_LDS16(gb + rowskip + k0, lB + 256 * 8);
        __syncthreads();

        bf16x8 a[4], b[4];
#pragma unroll
        for (int m = 0; m < 4; ++m)
            a[m] = *(const bf16x8*)&As[(wr * 64 + m * 16 + lr) * 32 + lq * 8];
#pragma unroll
        for (int n = 0; n < 4; ++n)
            b[n] = *(const bf16x8*)&Bs[(wc * 64 + n * 16 + lr) * 32 + lq * 8];
#pragma unroll
        for (int m = 0; m < 4; ++m)
#pragma unroll
            for (int n = 0; n < 4; ++n)
                acc[m][n] = __builtin_amdgcn_mfma_f32_16x16x32_bf16(a[m], b[n], acc[m][n], 0, 0, 0);
    }

    float* outp = out + (size_t)(i0 + wr * 64) * V + n0 + wc * 64;
#pragma unroll
    for (int m = 0; m < 4; ++m) {
        const int r0 = m * 16 + lq * 4;
#pragma unroll
        for (int n = 0; n < 4; ++n) {
            const int cc = n * 16 + lr;
#pragma unroll
            for (int r = 0; r < 4; ++r)
                outp[(size_t)(r0 + r) * V + cc] = acc[m][n][r];
        }
    }
}

// ============================ FALLBACK PATH (fp32, no ws) ============================

__global__ __launch_bounds__(256) void adj_kernel(const float* __restrict__ x,
                                                  float* __restrict__ adj) {
    const int n  = blockIdx.z;
    const int i0 = blockIdx.y * 64;
    const int j0 = blockIdx.x * 64;

    __shared__ float Xi[64][65];
    __shared__ float Xj[64][65];

    const float* xn = x + (size_t)n * V * C;
    const int tid = threadIdx.x;
    const int lr = tid >> 4;
    const int lc = (tid & 15) << 2;
#pragma unroll
    for (int it = 0; it < 4; ++it) {
        const int r = lr + it * 16;
        float4 vi = *(const float4*)(xn + (size_t)(i0 + r) * C + lc);
        float4 vj = *(const float4*)(xn + (size_t)(j0 + r) * C + lc);
        Xi[r][lc + 0] = vi.x; Xi[r][lc + 1] = vi.y; Xi[r][lc + 2] = vi.z; Xi[r][lc + 3] = vi.w;
        Xj[r][lc + 0] = vj.x; Xj[r][lc + 1] = vj.y; Xj[r][lc + 2] = vj.z; Xj[r][lc + 3] = vj.w;
    }
    __syncthreads();

    const int ti = (tid >> 4) << 2;
    const int tj = (tid & 15) << 2;

    float acc[4][4] = {};
#pragma unroll 4
    for (int c = 0; c < C; ++c) {
        float ai[4], bj[4];
#pragma unroll
        for (int a = 0; a < 4; ++a) ai[a] = Xi[ti + a][c];
#pragma unroll
        for (int b = 0; b < 4; ++b) bj[b] = Xj[tj + b][c];
#pragma unroll
        for (int a = 0; a < 4; ++a)
#pragma unroll
            for (int b = 0; b < 4; ++b) {
                const float d = ai[a] - bj[b];
                acc[a][b] = fmaf(d, d, acc[a][b]);
            }
    }

    float* outb = adj + ((size_t)n * V + i0) * V + j0;
#pragma unroll
    for (int a = 0; a < 4; ++a) {
        float4 o0;
        o0.x = expf(-0.5f * sqrtf(acc[a][0]));
        o0.y = expf(-0.5f * sqrtf(acc[a][1]));
        o0.z = expf(-0.5f * sqrtf(acc[a][2]));
        o0.w = expf(-0.5f * sqrtf(acc[a][3]));
        *(float4*)(outb + (size_t)(ti + a) * V + tj) = o0;
    }
}

__global__ __launch_bounds__(256) void gemm_inplace(float* __restrict__ adjout,
                                                    const float* __restrict__ w) {
    const int n  = blockIdx.y;
    const int i0 = blockIdx.x * 8;

    __shared__ float rows[8][V];

    float* base = adjout + ((size_t)n * V + i0) * V;
    const int tid = threadIdx.x;

    for (int t = tid; t < (8 * V) / 4; t += 256) {
        const int r = t >> 9;
        const int c = (t & 511) << 2;
        float4 v = *(const float4*)(base + (size_t)r * V + c);
        rows[r][c + 0] = v.x; rows[r][c + 1] = v.y; rows[r][c + 2] = v.z; rows[r][c + 3] = v.w;
    }
    __syncthreads();

    float acc[8][8] = {};
    const int k0 = tid << 3;
    const float* wp = w + k0;

    for (int j = 0; j < V; ++j) {
        float a[8];
#pragma unroll
        for (int r = 0; r < 8; ++r) a[r] = rows[r][j];
        const float* wr = wp + (size_t)j * V;
        const float4 w0 = *(const float4*)(wr);
        const float4 w1 = *(const float4*)(wr + 4);
        const float wv[8] = {w0.x, w0.y, w0.z, w0.w, w1.x, w1.y, w1.z, w1.w};
#pragma unroll
        for (int r = 0; r < 8; ++r)
#pragma unroll
            for (int c = 0; c < 8; ++c)
                acc[r][c] = fmaf(a[r], wv[c], acc[r][c]);
    }

#pragma unroll
    for (int r = 0; r < 8; ++r) {
        float4 o0, o1;
        o0.x = acc[r][0]; o0.y = acc[r][1]; o0.z = acc[r][2]; o0.w = acc[r][3];
        o1.x = acc[r][4]; o1.y = acc[r][5]; o1.z = acc[r][6]; o1.w = acc[r][7];
        *(float4*)(base + (size_t)r * V + k0)     = o0;
        *(float4*)(base + (size_t)r * V + k0 + 4) = o1;
    }
}

// ---------------- in-place row softmax (mid-tier + fallback paths) ----------------
__global__ __launch_bounds__(256) void softmax_kernel(float* __restrict__ out) {
    const int row  = blockIdx.x * 4 + (threadIdx.x >> 6);
    const int lane = threadIdx.x & 63;
    float* p = out + (size_t)row * V;

    float4 v[8];
#pragma unroll
    for (int s = 0; s < 8; ++s)
        v[s] = *(const float4*)(p + (size_t)(s * 64 + lane) * 4);

    float m = -INFINITY;
#pragma unroll
    for (int s = 0; s < 8; ++s)
        m = fmaxf(m, fmaxf(fmaxf(v[s].x, v[s].y), fmaxf(v[s].z, v[s].w)));
#pragma unroll
    for (int o = 32; o; o >>= 1) m = fmaxf(m, __shfl_xor(m, o));

    float sum = 0.0f;
#pragma unroll
    for (int s = 0; s < 8; ++s) {
        v[s].x = expf(v[s].x - m);
        v[s].y = expf(v[s].y - m);
        v[s].z = expf(v[s].z - m);
        v[s].w = expf(v[s].w - m);
        sum += (v[s].x + v[s].y) + (v[s].z + v[s].w);
    }
#pragma unroll
    for (int o = 32; o; o >>= 1) sum += __shfl_xor(sum, o);

    const float inv = 1.0f / sum;
#pragma unroll
    for (int s = 0; s < 8; ++s) {
        float4 o4;
        o4.x = v[s].x * inv; o4.y = v[s].y * inv;
        o4.z = v[s].z * inv; o4.w = v[s].w * inv;
        *(float4*)(p + (size_t)(s * 64 + lane) * 4) = o4;
    }
}

extern "C" void kernel_launch(void* const* d_in, const int* in_sizes, int n_in,
                              void* d_out, int out_size, void* d_ws, size_t ws_size,
                              hipStream_t stream) {
    const float* x = (const float*)d_in[0];
    const float* w = (const float*)d_in[1];
    float* out = (float*)d_out;

    const size_t adj_elems = (size_t)M_TOTAL * V;                  // 33.5M
    const size_t wt_elems  = (size_t)V * V;                        // 4.2M
    const size_t need      = (adj_elems + wt_elems) * 2;           // 75,497,472 B
    const size_t exp_off   = need;                                 // bytes
    const size_t need_big  = exp_off + adj_elems * 2;              // 142,606,336 B

    if (ws_size >= need) {
        unsigned short* adjb = (unsigned short*)d_ws;
        unsigned short* wtb  = adjb + adj_elems;

        adj_mfma<<<dim3(V / 128, V / 128, NB), 256, 0, stream>>>(x, adjb);
        wt_kernel<<<dim3(V / 64, V / 64), 256, 0, stream>>>(w, wtb);

        if (ws_size >= need_big) {
            unsigned short* expw = (unsigned short*)((char*)d_ws + exp_off);
            hipError_t ok = hipFuncSetAttribute(
                reinterpret_cast<const void*>(&gemm_8ph<1>),
                hipFuncAttributeMaxDynamicSharedMemorySize, 131072);
            if (ok == hipSuccess) {
                gemm_8ph<1><<<512, 512, 131072, stream>>>(adjb, wtb, out, expw);
                normalize_kernel<<<M_TOTAL / 4, 256, 0, stream>>>(expw, out);
                return;
            }
        }
        hipError_t ok = hipFuncSetAttribute(
            reinterpret_cast<const void*>(&gemm_8ph<0>),
            hipFuncAttributeMaxDynamicSharedMemorySize, 131072);
        if (ok == hipSuccess) {
            gemm_8ph<0><<<512, 512, 131072, stream>>>(adjb, wtb, out, nullptr);
        } else {
            gemm_mfma<<<2048, 256, 0, stream>>>(adjb, wtb, out);
        }
        softmax_kernel<<<(NB * V) / 4, 256, 0, stream>>>(out);
    } else {
        dim3 g1(V / 64, V / 64, NB);
        adj_kernel<<<g1, 256, 0, stream>>>(x, out);
        dim3 g2(V / 8, NB);
        gemm_inplace<<<g2, 256, 0, stream>>>(out, w);
        softmax_kernel<<<(NB * V) / 4, 256, 0, stream>>>(out);
    }
}

// Round 9
// 201.678 us; speedup vs baseline: 1.0763x; 1.0763x over previous
//
#include <hip/hip_runtime.h>
#include <hip/hip_bf16.h>
#include <hip/hip_fp16.h>
#include <math.h>

#define V 2048
#define C 64
#define NB 8
#define M_TOTAL (NB * V)   // 16384 rows total

typedef __attribute__((ext_vector_type(8))) short bf16x8;
typedef __attribute__((ext_vector_type(4))) float f32x4;

static __device__ __forceinline__ unsigned short f2bf(float f) {
    __hip_bfloat16 h = __float2bfloat16(f);   // RNE
    return *reinterpret_cast<unsigned short*>(&h);
}
static __device__ __forceinline__ unsigned short f2h(float f) {
    __half h = __float2half(f);
    return *reinterpret_cast<unsigned short*>(&h);
}
static __device__ __forceinline__ float h2f(unsigned short u) {
    __half h = *reinterpret_cast<__half*>(&u);
    return __half2float(h);
}

#define GLOAD_LDS16(g, l)                                                        \
    __builtin_amdgcn_global_load_lds((const __attribute__((address_space(1))) void*)(g), \
                                     (__attribute__((address_space(3))) void*)(l), 16, 0, 0)

// ============================ FAST PATH (needs d_ws) ============================

// ---- adj via MFMA gram: adjb[n*V+i][j] = bf16(exp(-0.5*sqrt(qi+qj-2*G_ij))) ----
// q computed IN-BLOCK with the bit-identical MFMA chain on the same LDS bf16
// data, so diagonal d^2 == 0 exactly.
__global__ __launch_bounds__(256) void adj_mfma(const float* __restrict__ x,
                                                unsigned short* __restrict__ adjb) {
    const int n  = blockIdx.z;
    const int i0 = blockIdx.y * 128;
    const int j0 = blockIdx.x * 128;
    const size_t nV = (size_t)n * V;

    __shared__ short Xi[128][72];
    __shared__ short Xj[128][72];
    __shared__ float Qi[128];
    __shared__ float Qj[128];

    const float* xn = x + nV * C;
    const int tid = threadIdx.x;

    for (int idx = tid; idx < 1024; idx += 256) {
        const int row = idx >> 3;
        const int c8  = (idx & 7) * 8;
        float4 ai0 = *(const float4*)(xn + (size_t)(i0 + row) * C + c8);
        float4 ai1 = *(const float4*)(xn + (size_t)(i0 + row) * C + c8 + 4);
        float4 aj0 = *(const float4*)(xn + (size_t)(j0 + row) * C + c8);
        float4 aj1 = *(const float4*)(xn + (size_t)(j0 + row) * C + c8 + 4);
        bf16x8 pi, pj;
        pi[0] = (short)f2bf(ai0.x); pi[1] = (short)f2bf(ai0.y);
        pi[2] = (short)f2bf(ai0.z); pi[3] = (short)f2bf(ai0.w);
        pi[4] = (short)f2bf(ai1.x); pi[5] = (short)f2bf(ai1.y);
        pi[6] = (short)f2bf(ai1.z); pi[7] = (short)f2bf(ai1.w);
        pj[0] = (short)f2bf(aj0.x); pj[1] = (short)f2bf(aj0.y);
        pj[2] = (short)f2bf(aj0.z); pj[3] = (short)f2bf(aj0.w);
        pj[4] = (short)f2bf(aj1.x); pj[5] = (short)f2bf(aj1.y);
        pj[6] = (short)f2bf(aj1.z); pj[7] = (short)f2bf(aj1.w);
        *(bf16x8*)&Xi[row][c8] = pi;
        *(bf16x8*)&Xj[row][c8] = pj;
    }
    __syncthreads();

    const int wid  = tid >> 6;
    const int lane = tid & 63;
    const int wr = wid >> 1, wc = wid & 1;
    const int lr = lane & 15, lq = lane >> 4;

    // ---- in-block q (same chain as gram below) ----
#pragma unroll
    for (int gg = 0; gg < 2; ++gg) {
        const int g = wid * 2 + gg;             // 0..7
        {
            const short* xr = &Xi[g * 16 + lr][0];
            bf16x8 a0 = *(const bf16x8*)(xr + lq * 8);
            bf16x8 a1 = *(const bf16x8*)(xr + 32 + lq * 8);
            f32x4 qa = (f32x4){0.f, 0.f, 0.f, 0.f};
            qa = __builtin_amdgcn_mfma_f32_16x16x32_bf16(a0, a0, qa, 0, 0, 0);
            qa = __builtin_amdgcn_mfma_f32_16x16x32_bf16(a1, a1, qa, 0, 0, 0);
            if (lq == (lr >> 2)) Qi[g * 16 + lr] = qa[lr & 3];
        }
        {
            const short* xr = &Xj[g * 16 + lr][0];
            bf16x8 a0 = *(const bf16x8*)(xr + lq * 8);
            bf16x8 a1 = *(const bf16x8*)(xr + 32 + lq * 8);
            f32x4 qa = (f32x4){0.f, 0.f, 0.f, 0.f};
            qa = __builtin_amdgcn_mfma_f32_16x16x32_bf16(a0, a0, qa, 0, 0, 0);
            qa = __builtin_amdgcn_mfma_f32_16x16x32_bf16(a1, a1, qa, 0, 0, 0);
            if (lq == (lr >> 2)) Qj[g * 16 + lr] = qa[lr & 3];
        }
    }
    __syncthreads();

    bf16x8 a[4][2], b[4][2];
#pragma unroll
    for (int m = 0; m < 4; ++m) {
        a[m][0] = *(const bf16x8*)&Xi[wr * 64 + m * 16 + lr][lq * 8];
        a[m][1] = *(const bf16x8*)&Xi[wr * 64 + m * 16 + lr][32 + lq * 8];
    }
#pragma unroll
    for (int nn = 0; nn < 4; ++nn) {
        b[nn][0] = *(const bf16x8*)&Xj[wc * 64 + nn * 16 + lr][lq * 8];
        b[nn][1] = *(const bf16x8*)&Xj[wc * 64 + nn * 16 + lr][32 + lq * 8];
    }

#pragma unroll
    for (int m = 0; m < 4; ++m) {
#pragma unroll
        for (int nn = 0; nn < 4; ++nn) {
            f32x4 g = (f32x4){0.f, 0.f, 0.f, 0.f};
            g = __builtin_amdgcn_mfma_f32_16x16x32_bf16(a[m][0], b[nn][0], g, 0, 0, 0);
            g = __builtin_amdgcn_mfma_f32_16x16x32_bf16(a[m][1], b[nn][1], g, 0, 0, 0);
            const int col_l = wc * 64 + nn * 16 + lr;
            const float qj = Qj[col_l];
#pragma unroll
            for (int r = 0; r < 4; ++r) {
                const int row_l = wr * 64 + m * 16 + lq * 4 + r;
                float d2 = Qi[row_l] + qj - 2.0f * g[r];
                d2 = fmaxf(d2, 0.0f);
                const float e = __expf(-0.5f * sqrtf(d2));
                adjb[(nV + i0 + row_l) * V + j0 + col_l] = f2bf(e);
            }
        }
    }
}

// ---- W transpose to bf16 ----
__global__ __launch_bounds__(256) void wt_kernel(const float* __restrict__ w,
                                                 unsigned short* __restrict__ wt) {
    __shared__ float tile[64][65];
    const int r0 = blockIdx.y * 64, c0 = blockIdx.x * 64;
    const int tr = threadIdx.x >> 4;
    const int tc4 = (threadIdx.x & 15) << 2;
#pragma unroll
    for (int it = 0; it < 4; ++it) {
        const int r = tr + 16 * it;
        float4 v = *(const float4*)(w + (size_t)(r0 + r) * V + c0 + tc4);
        tile[r][tc4 + 0] = v.x; tile[r][tc4 + 1] = v.y;
        tile[r][tc4 + 2] = v.z; tile[r][tc4 + 3] = v.w;
    }
    __syncthreads();
#pragma unroll
    for (int it = 0; it < 4; ++it) {
        const int cr = tr + 16 * it;
        ushort4 o;
        o.x = f2bf(tile[tc4 + 0][cr]);
        o.y = f2bf(tile[tc4 + 1][cr]);
        o.z = f2bf(tile[tc4 + 2][cr]);
        o.w = f2bf(tile[tc4 + 3][cr]);
        *(ushort4*)(wt + (size_t)(c0 + cr) * V + r0 + tc4) = o;
    }
}

// ============== 256x256 8-phase MFMA GEMM (T2+T3+T4+T5 template) ==============
// Round-6 proven config: 16x16x32 fragments (the swizzle is co-designed with
// this shape: 16 rows x 4 col-slots -> 0 bank conflicts. Round-8 lesson: the
// same swizzle with 32x32 frags (32 rows x 1 col-slot) = 4-way conflict, -12%).
// FUSED=1 epilogue: e = __expf(logit) stored fp16 (no max-sub: logits in
// [0,~15]; softmax shift-invariant). Row sums deferred to normalize (BW-bound,
// VALU free there -- round-5 lesson).
__device__ __forceinline__ void stage_region(char* smem, int regionOff,
                                             const unsigned short* gbase,
                                             int tile, int ks, int tid) {
#pragma unroll
    for (int s = 0; s < 2; ++s) {
        const int off = s * 8192 + tid * 16;       // linear LDS byte offset
        const int row = off >> 6;
        const int pb  = off & 63;
        const int lb  = pb ^ (((row >> 1) & 3) << 4);  // inverse swizzle on source
        const unsigned short* g = gbase + (size_t)row * V + tile * 64 + ks * 32 + (lb >> 1);
        GLOAD_LDS16(g, smem + regionOff + off);
    }
}

#define LDS_FRAG(BUF, BOFF, KS, ROW)                                             \
    (*(const bf16x8*)(smem + (BUF) * 65536 + (BOFF) + (KS) * 16384 +             \
                      (ROW) * 64 + (lqb ^ ((((ROW) >> 1) & 3) << 4))))

#define PHASE(BUF, MS, KS, LOADB, STAGE_STMT, WAITV)                             \
    {                                                                            \
        bf16x8 af[4];                                                            \
        _Pragma("unroll") for (int m = 0; m < 4; ++m) {                          \
            const int row = wr128 + ((MS) + m) * 16 + lr;                        \
            af[m] = LDS_FRAG(BUF, 0, KS, row);                                   \
        }                                                                        \
        if (LOADB) {                                                             \
            _Pragma("unroll") for (int n = 0; n < 4; ++n) {                      \
                const int row = wc64 + n * 16 + lr;                              \
                bf[n] = LDS_FRAG(BUF, 32768, KS, row);                           \
            }                                                                    \
        }                                                                        \
        STAGE_STMT;                                                              \
        if (WAITV) {                                                             \
            asm volatile("s_waitcnt vmcnt(6)" ::: "memory");                     \
            __builtin_amdgcn_sched_barrier(0);                                   \
        }                                                                        \
        __builtin_amdgcn_s_barrier();                                            \
        asm volatile("s_waitcnt lgkmcnt(0)" ::: "memory");                       \
        __builtin_amdgcn_sched_barrier(0);                                       \
        __builtin_amdgcn_s_setprio(1);                                           \
        _Pragma("unroll") for (int m = 0; m < 4; ++m)                            \
            _Pragma("unroll") for (int n = 0; n < 4; ++n)                        \
                acc[(MS) + m][n] = __builtin_amdgcn_mfma_f32_16x16x32_bf16(      \
                    af[m], bf[n], acc[(MS) + m][n], 0, 0, 0);                    \
        __builtin_amdgcn_s_setprio(0);                                           \
        __builtin_amdgcn_s_barrier();                                            \
    }

template <int FUSED>
__global__ __launch_bounds__(512, 2) void gemm_8ph(const unsigned short* __restrict__ adjb,
                                                   const unsigned short* __restrict__ wtb,
                                                   float* __restrict__ out,
                                                   unsigned short* __restrict__ expw) {
    extern __shared__ char smem[];

    const int bid = blockIdx.x;
    const int swz = (bid & 7) * 64 + (bid >> 3);   // bijective XCD swizzle (512%8==0)
    const int by = swz >> 3;            // 0..63
    const int bx = swz & 7;             // 0..7
    const int i0 = by * 256;
    const int n0 = bx * 256;

    const int tid  = threadIdx.x;
    const int wid  = tid >> 6;
    const int lane = tid & 63;
    const int wr = wid >> 2, wc = wid & 3;        // 2 x 4 waves
    const int wr128 = wr * 128, wc64 = wc * 64;
    const int lr = lane & 15, lq = lane >> 4;
    const int lqb = lq * 16;

    const unsigned short* gA = adjb + (size_t)i0 * V;
    const unsigned short* gB = wtb  + (size_t)n0 * V;

    f32x4 acc[8][4];
#pragma unroll
    for (int m = 0; m < 8; ++m)
#pragma unroll
        for (int n = 0; n < 4; ++n) acc[m][n] = (f32x4){0.f, 0.f, 0.f, 0.f};

    // prologue: buf0 <- tile0 (4 regions), buf1 <- tile1 (Bk0,Ak0,Bk1)
    stage_region(smem, 32768,         gB, 0, 0, tid);
    stage_region(smem, 0,             gA, 0, 0, tid);
    stage_region(smem, 49152,         gB, 0, 1, tid);
    stage_region(smem, 16384,         gA, 0, 1, tid);
    stage_region(smem, 65536 + 32768, gB, 1, 0, tid);
    stage_region(smem, 65536 + 0,     gA, 1, 0, tid);
    stage_region(smem, 65536 + 49152, gB, 1, 1, tid);
    asm volatile("s_waitcnt vmcnt(6)" ::: "memory");
    __builtin_amdgcn_sched_barrier(0);
    __builtin_amdgcn_s_barrier();

    bf16x8 bf[4];

#pragma unroll 1
    for (int i = 0; i < 16; ++i) {
        const int t1b = 2 * i + 1;
        const int t2  = (2 * i + 2 < 32) ? 2 * i + 2 : 31;   // clamp: idempotent tail
        const int t3  = (2 * i + 3 < 32) ? 2 * i + 3 : 31;

        PHASE(0, 0, 0, true,  stage_region(smem, 65536 + 16384, gA, t1b, 1, tid), false)
        PHASE(0, 4, 0, false, stage_region(smem, 32768,         gB, t2,  0, tid), false)
        PHASE(0, 0, 1, true,  stage_region(smem, 0,             gA, t2,  0, tid), false)
        PHASE(0, 4, 1, false, stage_region(smem, 49152,         gB, t2,  1, tid), true)
        PHASE(1, 0, 0, true,  stage_region(smem, 16384,         gA, t2,  1, tid), false)
        PHASE(1, 4, 0, false, stage_region(smem, 65536 + 32768, gB, t3,  0, tid), false)
        PHASE(1, 0, 1, true,  stage_region(smem, 65536 + 0,     gA, t3,  0, tid), false)
        PHASE(1, 4, 1, false, stage_region(smem, 65536 + 49152, gB, t3,  1, tid), true)
    }

    if (FUSED) {
        // softmax stage 1 (store only): e = exp(logit), fp16.
        unsigned short* ep = expw + (size_t)(i0 + wr128) * V + n0 + wc64;
#pragma unroll
        for (int m = 0; m < 8; ++m) {
#pragma unroll
            for (int r = 0; r < 4; ++r) {
                unsigned short* p = ep + (size_t)(m * 16 + lq * 4 + r) * V;
#pragma unroll
                for (int n = 0; n < 4; ++n)
                    p[n * 16 + lr] = f2h(__expf(acc[m][n][r]));
            }
        }
    } else {
        float* op = out + (size_t)(i0 + wr128) * V + n0 + wc64;
#pragma unroll
        for (int m = 0; m < 8; ++m)
#pragma unroll
            for (int n = 0; n < 4; ++n)
#pragma unroll
                for (int r = 0; r < 4; ++r)
                    op[(size_t)(m * 16 + lq * 4 + r) * V + n * 16 + lr] = acc[m][n][r];
    }
}

// ---- softmax stage 2: single pass — sum fp16 exp row, scale, write fp32 (nt) ----
__global__ __launch_bounds__(256) void normalize_kernel(const unsigned short* __restrict__ expw,
                                                        float* __restrict__ out) {
    const int row  = blockIdx.x * 4 + (threadIdx.x >> 6);
    const int lane = threadIdx.x & 63;

    const unsigned short* ip = expw + (size_t)row * V;
    float* op = out + (size_t)row * V;

    float v[32];
    float sum = 0.0f;
#pragma unroll
    for (int t = 0; t < 4; ++t) {
        const int base = (t * 64 + lane) * 8;
        ushort4 u0 = *(const ushort4*)(ip + base);
        ushort4 u1 = *(const ushort4*)(ip + base + 4);
        v[t * 8 + 0] = h2f(u0.x); v[t * 8 + 1] = h2f(u0.y);
        v[t * 8 + 2] = h2f(u0.z); v[t * 8 + 3] = h2f(u0.w);
        v[t * 8 + 4] = h2f(u1.x); v[t * 8 + 5] = h2f(u1.y);
        v[t * 8 + 6] = h2f(u1.z); v[t * 8 + 7] = h2f(u1.w);
#pragma unroll
        for (int k = 0; k < 8; ++k) sum += v[t * 8 + k];
    }
#pragma unroll
    for (int o = 32; o; o >>= 1) sum += __shfl_xor(sum, o);
    const float inv = 1.0f / sum;

#pragma unroll
    for (int t = 0; t < 4; ++t) {
        const int base = (t * 64 + lane) * 8;
        f32x4 o0, o1;
        o0[0] = v[t * 8 + 0] * inv; o0[1] = v[t * 8 + 1] * inv;
        o0[2] = v[t * 8 + 2] * inv; o0[3] = v[t * 8 + 3] * inv;
        o1[0] = v[t * 8 + 4] * inv; o1[1] = v[t * 8 + 5] * inv;
        o1[2] = v[t * 8 + 6] * inv; o1[3] = v[t * 8 + 7] * inv;
        __builtin_nontemporal_store(o0, (f32x4*)(op + base));
        __builtin_nontemporal_store(o1, (f32x4*)(op + base + 4));
    }
}

// ---- backup MFMA GEMM (proven round-3 kernel) ----
__global__ __launch_bounds__(256) void gemm_mfma(const unsigned short* __restrict__ adjb,
                                                 const unsigned short* __restrict__ wtb,
                                                 float* __restrict__ out) {
    const int bid = blockIdx.x;
    const int swz = (bid & 7) * 256 + (bid >> 3);
    const int by = swz >> 4;
    const int bx = swz & 15;
    const int i0 = by * 128;
    const int n0 = bx * 128;

    __shared__ alignas(16) unsigned short As[128 * 32];
    __shared__ alignas(16) unsigned short Bs[128 * 32];

    const int tid  = threadIdx.x;
    const int wid  = tid >> 6;
    const int lane = tid & 63;
    const int wr = wid >> 1, wc = wid & 1;
    const int lr = lane & 15, lq = lane >> 4;

    f32x4 acc[4][4];
#pragma unroll
    for (int m = 0; m < 4; ++m)
#pragma unroll
        for (int n = 0; n < 4; ++n) acc[m][n] = (f32x4){0.f, 0.f, 0.f, 0.f};

    const unsigned short* ga = adjb + (size_t)(i0 + (tid >> 2)) * V + (tid & 3) * 8;
    const unsigned short* gb = wtb  + (size_t)(n0 + (tid >> 2)) * V + (tid & 3) * 8;
    unsigned short* lA = &As[tid * 8];
    unsigned short* lB = &Bs[tid * 8];
    const size_t rowskip = (size_t)64 * V;

    for (int kt = 0; kt < 64; ++kt) {
        const int k0 = kt * 32;
        if (kt) __syncthreads();
        GLOAD_LDS16(ga + k0,           lA);
        GLOAD_LDS16(ga + rowskip + k0, lA + 256 * 8);
        GLOAD_LDS16(gb + k0,           lB);
        GLOAD_LDS16(gb + rowskip + k0, lB + 256 * 8);
        __syncthreads();

        bf16x8 a[4], b[4];
#pragma unroll
        for (int m = 0; m < 4; ++m)
            a[m] = *(const bf16x8*)&As[(wr * 64 + m * 16 + lr) * 32 + lq * 8];
#pragma unroll
        for (int n = 0; n < 4; ++n)
            b[n] = *(const bf16x8*)&Bs[(wc * 64 + n * 16 + lr) * 32 + lq * 8];
#pragma unroll
        for (int m = 0; m < 4; ++m)
#pragma unroll
            for (int n = 0; n < 4; ++n)
                acc[m][n] = __builtin_amdgcn_mfma_f32_16x16x32_bf16(a[m], b[n], acc[m][n], 0, 0, 0);
    }

    float* outp = out + (size_t)(i0 + wr * 64) * V + n0 + wc * 64;
#pragma unroll
    for (int m = 0; m < 4; ++m) {
        const int r0 = m * 16 + lq * 4;
#pragma unroll
        for (int n = 0; n < 4; ++n) {
            const int cc = n * 16 + lr;
#pragma unroll
            for (int r = 0; r < 4; ++r)
                outp[(size_t)(r0 + r) * V + cc] = acc[m][n][r];
        }
    }
}

// ============================ FALLBACK PATH (fp32, no ws) ============================

__global__ __launch_bounds__(256) void adj_kernel(const float* __restrict__ x,
                                                  float* __restrict__ adj) {
    const int n  = blockIdx.z;
    const int i0 = blockIdx.y * 64;
    const int j0 = blockIdx.x * 64;

    __shared__ float Xi[64][65];
    __shared__ float Xj[64][65];

    const float* xn = x + (size_t)n * V * C;
    const int tid = threadIdx.x;
    const int lr = tid >> 4;
    const int lc = (tid & 15) << 2;
#pragma unroll
    for (int it = 0; it < 4; ++it) {
        const int r = lr + it * 16;
        float4 vi = *(const float4*)(xn + (size_t)(i0 + r) * C + lc);
        float4 vj = *(const float4*)(xn + (size_t)(j0 + r) * C + lc);
        Xi[r][lc + 0] = vi.x; Xi[r][lc + 1] = vi.y; Xi[r][lc + 2] = vi.z; Xi[r][lc + 3] = vi.w;
        Xj[r][lc + 0] = vj.x; Xj[r][lc + 1] = vj.y; Xj[r][lc + 2] = vj.z; Xj[r][lc + 3] = vj.w;
    }
    __syncthreads();

    const int ti = (tid >> 4) << 2;
    const int tj = (tid & 15) << 2;

    float acc[4][4] = {};
#pragma unroll 4
    for (int c = 0; c < C; ++c) {
        float ai[4], bj[4];
#pragma unroll
        for (int a = 0; a < 4; ++a) ai[a] = Xi[ti + a][c];
#pragma unroll
        for (int b = 0; b < 4; ++b) bj[b] = Xj[tj + b][c];
#pragma unroll
        for (int a = 0; a < 4; ++a)
#pragma unroll
            for (int b = 0; b < 4; ++b) {
                const float d = ai[a] - bj[b];
                acc[a][b] = fmaf(d, d, acc[a][b]);
            }
    }

    float* outb = adj + ((size_t)n * V + i0) * V + j0;
#pragma unroll
    for (int a = 0; a < 4; ++a) {
        float4 o0;
        o0.x = expf(-0.5f * sqrtf(acc[a][0]));
        o0.y = expf(-0.5f * sqrtf(acc[a][1]));
        o0.z = expf(-0.5f * sqrtf(acc[a][2]));
        o0.w = expf(-0.5f * sqrtf(acc[a][3]));
        *(float4*)(outb + (size_t)(ti + a) * V + tj) = o0;
    }
}

__global__ __launch_bounds__(256) void gemm_inplace(float* __restrict__ adjout,
                                                    const float* __restrict__ w) {
    const int n  = blockIdx.y;
    const int i0 = blockIdx.x * 8;

    __shared__ float rows[8][V];

    float* base = adjout + ((size_t)n * V + i0) * V;
    const int tid = threadIdx.x;

    for (int t = tid; t < (8 * V) / 4; t += 256) {
        const int r = t >> 9;
        const int c = (t & 511) << 2;
        float4 v = *(const float4*)(base + (size_t)r * V + c);
        rows[r][c + 0] = v.x; rows[r][c + 1] = v.y; rows[r][c + 2] = v.z; rows[r][c + 3] = v.w;
    }
    __syncthreads();

    float acc[8][8] = {};
    const int k0 = tid << 3;
    const float* wp = w + k0;

    for (int j = 0; j < V; ++j) {
        float a[8];
#pragma unroll
        for (int r = 0; r < 8; ++r) a[r] = rows[r][j];
        const float* wr = wp + (size_t)j * V;
        const float4 w0 = *(const float4*)(wr);
        const float4 w1 = *(const float4*)(wr + 4);
        const float wv[8] = {w0.x, w0.y, w0.z, w0.w, w1.x, w1.y, w1.z, w1.w};
#pragma unroll
        for (int r = 0; r < 8; ++r)
#pragma unroll
            for (int c = 0; c < 8; ++c)
                acc[r][c] = fmaf(a[r], wv[c], acc[r][c]);
    }

#pragma unroll
    for (int r = 0; r < 8; ++r) {
        float4 o0, o1;
        o0.x = acc[r][0]; o0.y = acc[r][1]; o0.z = acc[r][2]; o0.w = acc[r][3];
        o1.x = acc[r][4]; o1.y = acc[r][5]; o1.z = acc[r][6]; o1.w = acc[r][7];
        *(float4*)(base + (size_t)r * V + k0)     = o0;
        *(float4*)(base + (size_t)r * V + k0 + 4) = o1;
    }
}

// ---------------- in-place row softmax (mid-tier + fallback paths) ----------------
__global__ __launch_bounds__(256) void softmax_kernel(float* __restrict__ out) {
    const int row  = blockIdx.x * 4 + (threadIdx.x >> 6);
    const int lane = threadIdx.x & 63;
    float* p = out + (size_t)row * V;

    float4 v[8];
#pragma unroll
    for (int s = 0; s < 8; ++s)
        v[s] = *(const float4*)(p + (size_t)(s * 64 + lane) * 4);

    float m = -INFINITY;
#pragma unroll
    for (int s = 0; s < 8; ++s)
        m = fmaxf(m, fmaxf(fmaxf(v[s].x, v[s].y), fmaxf(v[s].z, v[s].w)));
#pragma unroll
    for (int o = 32; o; o >>= 1) m = fmaxf(m, __shfl_xor(m, o));

    float sum = 0.0f;
#pragma unroll
    for (int s = 0; s < 8; ++s) {
        v[s].x = expf(v[s].x - m);
        v[s].y = expf(v[s].y - m);
        v[s].z = expf(v[s].z - m);
        v[s].w = expf(v[s].w - m);
        sum += (v[s].x + v[s].y) + (v[s].z + v[s].w);
    }
#pragma unroll
    for (int o = 32; o; o >>= 1) sum += __shfl_xor(sum, o);

    const float inv = 1.0f / sum;
#pragma unroll
    for (int s = 0; s < 8; ++s) {
        float4 o4;
        o4.x = v[s].x * inv; o4.y = v[s].y * inv;
        o4.z = v[s].z * inv; o4.w = v[s].w * inv;
        *(float4*)(p + (size_t)(s * 64 + lane) * 4) = o4;
    }
}

extern "C" void kernel_launch(void* const* d_in, const int* in_sizes, int n_in,
                              void* d_out, int out_size, void* d_ws, size_t ws_size,
                              hipStream_t stream) {
    const float* x = (const float*)d_in[0];
    const float* w = (const float*)d_in[1];
    float* out = (float*)d_out;

    const size_t adj_elems = (size_t)M_TOTAL * V;                  // 33.5M
    const size_t wt_elems  = (size_t)V * V;                        // 4.2M
    const size_t need      = (adj_elems + wt_elems) * 2;           // 75,497,472 B
    const size_t exp_off   = need;                                 // bytes
    const size_t need_big  = exp_off + adj_elems * 2;              // 142,606,336 B

    if (ws_size >= need) {
        unsigned short* adjb = (unsigned short*)d_ws;
        unsigned short* wtb  = adjb + adj_elems;

        adj_mfma<<<dim3(V / 128, V / 128, NB), 256, 0, stream>>>(x, adjb);
        wt_kernel<<<dim3(V / 64, V / 64), 256, 0, stream>>>(w, wtb);

        if (ws_size >= need_big) {
            unsigned short* expw = (unsigned short*)((char*)d_ws + exp_off);
            hipError_t ok = hipFuncSetAttribute(
                reinterpret_cast<const void*>(&gemm_8ph<1>),
                hipFuncAttributeMaxDynamicSharedMemorySize, 131072);
            if (ok == hipSuccess) {
                gemm_8ph<1><<<512, 512, 131072, stream>>>(adjb, wtb, out, expw);
                normalize_kernel<<<M_TOTAL / 4, 256, 0, stream>>>(expw, out);
                return;
            }
        }
        hipError_t ok = hipFuncSetAttribute(
            reinterpret_cast<const void*>(&gemm_8ph<0>),
            hipFuncAttributeMaxDynamicSharedMemorySize, 131072);
        if (ok == hipSuccess) {
            gemm_8ph<0><<<512, 512, 131072, stream>>>(adjb, wtb, out, nullptr);
        } else {
            gemm_mfma<<<2048, 256, 0, stream>>>(adjb, wtb, out);
        }
        softmax_kernel<<<(NB * V) / 4, 256, 0, stream>>>(out);
    } else {
        dim3 g1(V / 64, V / 64, NB);
        adj_kernel<<<g1, 256, 0, stream>>>(x, out);
        dim3 g2(V / 8, NB);
        gemm_inplace<<<g2, 256, 0, stream>>>(out, w);
        softmax_kernel<<<(NB * V) / 4, 256, 0, stream>>>(out);
    }
}

// Round 10
// 188.815 us; speedup vs baseline: 1.1496x; 1.0681x over previous
//
#include <hip/hip_runtime.h>
#include <hip/hip_bf16.h>
#include <hip/hip_fp16.h>
#include <math.h>

#define V 2048
#define C 64
#define NB 8
#define M_TOTAL (NB * V)   // 16384 rows total

typedef __attribute__((ext_vector_type(8))) short bf16x8;
typedef __attribute__((ext_vector_type(4))) float f32x4;

static __device__ __forceinline__ unsigned short f2bf(float f) {
    __hip_bfloat16 h = __float2bfloat16(f);   // RNE
    return *reinterpret_cast<unsigned short*>(&h);
}
static __device__ __forceinline__ unsigned short f2h(float f) {
    __half h = __float2half(f);
    return *reinterpret_cast<unsigned short*>(&h);
}
static __device__ __forceinline__ float h2f(unsigned short u) {
    __half h = *reinterpret_cast<__half*>(&u);
    return __half2float(h);
}

#define GLOAD_LDS16(g, l)                                                        \
    __builtin_amdgcn_global_load_lds((const __attribute__((address_space(1))) void*)(g), \
                                     (__attribute__((address_space(3))) void*)(l), 16, 0, 0)

// ============================ FAST PATH (needs d_ws) ============================

// ---- adj via MFMA gram: adjb[n*V+i][j] = bf16(exp(-0.5*sqrt(qi+qj-2*G_ij))) ----
// q computed IN-BLOCK with the bit-identical MFMA chain on the same LDS bf16
// data, so diagonal d^2 == 0 exactly.
__global__ __launch_bounds__(256) void adj_mfma(const float* __restrict__ x,
                                                unsigned short* __restrict__ adjb) {
    const int n  = blockIdx.z;
    const int i0 = blockIdx.y * 128;
    const int j0 = blockIdx.x * 128;
    const size_t nV = (size_t)n * V;

    __shared__ short Xi[128][72];
    __shared__ short Xj[128][72];
    __shared__ float Qi[128];
    __shared__ float Qj[128];

    const float* xn = x + nV * C;
    const int tid = threadIdx.x;

    for (int idx = tid; idx < 1024; idx += 256) {
        const int row = idx >> 3;
        const int c8  = (idx & 7) * 8;
        float4 ai0 = *(const float4*)(xn + (size_t)(i0 + row) * C + c8);
        float4 ai1 = *(const float4*)(xn + (size_t)(i0 + row) * C + c8 + 4);
        float4 aj0 = *(const float4*)(xn + (size_t)(j0 + row) * C + c8);
        float4 aj1 = *(const float4*)(xn + (size_t)(j0 + row) * C + c8 + 4);
        bf16x8 pi, pj;
        pi[0] = (short)f2bf(ai0.x); pi[1] = (short)f2bf(ai0.y);
        pi[2] = (short)f2bf(ai0.z); pi[3] = (short)f2bf(ai0.w);
        pi[4] = (short)f2bf(ai1.x); pi[5] = (short)f2bf(ai1.y);
        pi[6] = (short)f2bf(ai1.z); pi[7] = (short)f2bf(ai1.w);
        pj[0] = (short)f2bf(aj0.x); pj[1] = (short)f2bf(aj0.y);
        pj[2] = (short)f2bf(aj0.z); pj[3] = (short)f2bf(aj0.w);
        pj[4] = (short)f2bf(aj1.x); pj[5] = (short)f2bf(aj1.y);
        pj[6] = (short)f2bf(aj1.z); pj[7] = (short)f2bf(aj1.w);
        *(bf16x8*)&Xi[row][c8] = pi;
        *(bf16x8*)&Xj[row][c8] = pj;
    }
    __syncthreads();

    const int wid  = tid >> 6;
    const int lane = tid & 63;
    const int wr = wid >> 1, wc = wid & 1;
    const int lr = lane & 15, lq = lane >> 4;

    // ---- in-block q (same chain as gram below) ----
#pragma unroll
    for (int gg = 0; gg < 2; ++gg) {
        const int g = wid * 2 + gg;             // 0..7
        {
            const short* xr = &Xi[g * 16 + lr][0];
            bf16x8 a0 = *(const bf16x8*)(xr + lq * 8);
            bf16x8 a1 = *(const bf16x8*)(xr + 32 + lq * 8);
            f32x4 qa = (f32x4){0.f, 0.f, 0.f, 0.f};
            qa = __builtin_amdgcn_mfma_f32_16x16x32_bf16(a0, a0, qa, 0, 0, 0);
            qa = __builtin_amdgcn_mfma_f32_16x16x32_bf16(a1, a1, qa, 0, 0, 0);
            if (lq == (lr >> 2)) Qi[g * 16 + lr] = qa[lr & 3];
        }
        {
            const short* xr = &Xj[g * 16 + lr][0];
            bf16x8 a0 = *(const bf16x8*)(xr + lq * 8);
            bf16x8 a1 = *(const bf16x8*)(xr + 32 + lq * 8);
            f32x4 qa = (f32x4){0.f, 0.f, 0.f, 0.f};
            qa = __builtin_amdgcn_mfma_f32_16x16x32_bf16(a0, a0, qa, 0, 0, 0);
            qa = __builtin_amdgcn_mfma_f32_16x16x32_bf16(a1, a1, qa, 0, 0, 0);
            if (lq == (lr >> 2)) Qj[g * 16 + lr] = qa[lr & 3];
        }
    }
    __syncthreads();

    bf16x8 a[4][2], b[4][2];
#pragma unroll
    for (int m = 0; m < 4; ++m) {
        a[m][0] = *(const bf16x8*)&Xi[wr * 64 + m * 16 + lr][lq * 8];
        a[m][1] = *(const bf16x8*)&Xi[wr * 64 + m * 16 + lr][32 + lq * 8];
    }
#pragma unroll
    for (int nn = 0; nn < 4; ++nn) {
        b[nn][0] = *(const bf16x8*)&Xj[wc * 64 + nn * 16 + lr][lq * 8];
        b[nn][1] = *(const bf16x8*)&Xj[wc * 64 + nn * 16 + lr][32 + lq * 8];
    }

#pragma unroll
    for (int m = 0; m < 4; ++m) {
#pragma unroll
        for (int nn = 0; nn < 4; ++nn) {
            f32x4 g = (f32x4){0.f, 0.f, 0.f, 0.f};
            g = __builtin_amdgcn_mfma_f32_16x16x32_bf16(a[m][0], b[nn][0], g, 0, 0, 0);
            g = __builtin_amdgcn_mfma_f32_16x16x32_bf16(a[m][1], b[nn][1], g, 0, 0, 0);
            const int col_l = wc * 64 + nn * 16 + lr;
            const float qj = Qj[col_l];
#pragma unroll
            for (int r = 0; r < 4; ++r) {
                const int row_l = wr * 64 + m * 16 + lq * 4 + r;
                float d2 = Qi[row_l] + qj - 2.0f * g[r];
                d2 = fmaxf(d2, 0.0f);
                const float e = __expf(-0.5f * sqrtf(d2));
                adjb[(nV + i0 + row_l) * V + j0 + col_l] = f2bf(e);
            }
        }
    }
}

// ---- W transpose to bf16 ----
__global__ __launch_bounds__(256) void wt_kernel(const float* __restrict__ w,
                                                 unsigned short* __restrict__ wt) {
    __shared__ float tile[64][65];
    const int r0 = blockIdx.y * 64, c0 = blockIdx.x * 64;
    const int tr = threadIdx.x >> 4;
    const int tc4 = (threadIdx.x & 15) << 2;
#pragma unroll
    for (int it = 0; it < 4; ++it) {
        const int r = tr + 16 * it;
        float4 v = *(const float4*)(w + (size_t)(r0 + r) * V + c0 + tc4);
        tile[r][tc4 + 0] = v.x; tile[r][tc4 + 1] = v.y;
        tile[r][tc4 + 2] = v.z; tile[r][tc4 + 3] = v.w;
    }
    __syncthreads();
#pragma unroll
    for (int it = 0; it < 4; ++it) {
        const int cr = tr + 16 * it;
        ushort4 o;
        o.x = f2bf(tile[tc4 + 0][cr]);
        o.y = f2bf(tile[tc4 + 1][cr]);
        o.z = f2bf(tile[tc4 + 2][cr]);
        o.w = f2bf(tile[tc4 + 3][cr]);
        *(ushort4*)(wt + (size_t)(c0 + cr) * V + r0 + tc4) = o;
    }
}

// ============== 256x256 8-phase MFMA GEMM (T2+T3+T4+T5 template) ==============
// Round-6 proven config: 16x16x32 fragments (the swizzle is co-designed with
// this shape: 16 rows x 4 col-slots -> 0 bank conflicts. Round-8 lesson: the
// same swizzle with 32x32 frags (32 rows x 1 col-slot) = 4-way conflict, -12%).
// FUSED=1 epilogue: e = __expf(logit) stored fp16 (no max-sub: logits in
// [0,~15]; softmax shift-invariant). Row sums deferred to normalize (BW-bound,
// VALU free there -- round-5 lesson). Plain stores everywhere (round-9 lesson:
// nontemporal stores on the bulk output stream cost ~13 us).
__device__ __forceinline__ void stage_region(char* smem, int regionOff,
                                             const unsigned short* gbase,
                                             int tile, int ks, int tid) {
#pragma unroll
    for (int s = 0; s < 2; ++s) {
        const int off = s * 8192 + tid * 16;       // linear LDS byte offset
        const int row = off >> 6;
        const int pb  = off & 63;
        const int lb  = pb ^ (((row >> 1) & 3) << 4);  // inverse swizzle on source
        const unsigned short* g = gbase + (size_t)row * V + tile * 64 + ks * 32 + (lb >> 1);
        GLOAD_LDS16(g, smem + regionOff + off);
    }
}

#define LDS_FRAG(BUF, BOFF, KS, ROW)                                             \
    (*(const bf16x8*)(smem + (BUF) * 65536 + (BOFF) + (KS) * 16384 +             \
                      (ROW) * 64 + (lqb ^ ((((ROW) >> 1) & 3) << 4))))

#define PHASE(BUF, MS, KS, LOADB, STAGE_STMT, WAITV)                             \
    {                                                                            \
        bf16x8 af[4];                                                            \
        _Pragma("unroll") for (int m = 0; m < 4; ++m) {                          \
            const int row = wr128 + ((MS) + m) * 16 + lr;                        \
            af[m] = LDS_FRAG(BUF, 0, KS, row);                                   \
        }                                                                        \
        if (LOADB) {                                                             \
            _Pragma("unroll") for (int n = 0; n < 4; ++n) {                      \
                const int row = wc64 + n * 16 + lr;                              \
                bf[n] = LDS_FRAG(BUF, 32768, KS, row);                           \
            }                                                                    \
        }                                                                        \
        STAGE_STMT;                                                              \
        if (WAITV) {                                                             \
            asm volatile("s_waitcnt vmcnt(6)" ::: "memory");                     \
            __builtin_amdgcn_sched_barrier(0);                                   \
        }                                                                        \
        __builtin_amdgcn_s_barrier();                                            \
        asm volatile("s_waitcnt lgkmcnt(0)" ::: "memory");                       \
        __builtin_amdgcn_sched_barrier(0);                                       \
        __builtin_amdgcn_s_setprio(1);                                           \
        _Pragma("unroll") for (int m = 0; m < 4; ++m)                            \
            _Pragma("unroll") for (int n = 0; n < 4; ++n)                        \
                acc[(MS) + m][n] = __builtin_amdgcn_mfma_f32_16x16x32_bf16(      \
                    af[m], bf[n], acc[(MS) + m][n], 0, 0, 0);                    \
        __builtin_amdgcn_s_setprio(0);                                           \
        __builtin_amdgcn_s_barrier();                                            \
    }

template <int FUSED>
__global__ __launch_bounds__(512, 2) void gemm_8ph(const unsigned short* __restrict__ adjb,
                                                   const unsigned short* __restrict__ wtb,
                                                   float* __restrict__ out,
                                                   unsigned short* __restrict__ expw) {
    extern __shared__ char smem[];

    const int bid = blockIdx.x;
    const int swz = (bid & 7) * 64 + (bid >> 3);   // bijective XCD swizzle (512%8==0)
    const int by = swz >> 3;            // 0..63
    const int bx = swz & 7;             // 0..7
    const int i0 = by * 256;
    const int n0 = bx * 256;

    const int tid  = threadIdx.x;
    const int wid  = tid >> 6;
    const int lane = tid & 63;
    const int wr = wid >> 2, wc = wid & 3;        // 2 x 4 waves
    const int wr128 = wr * 128, wc64 = wc * 64;
    const int lr = lane & 15, lq = lane >> 4;
    const int lqb = lq * 16;

    const unsigned short* gA = adjb + (size_t)i0 * V;
    const unsigned short* gB = wtb  + (size_t)n0 * V;

    f32x4 acc[8][4];
#pragma unroll
    for (int m = 0; m < 8; ++m)
#pragma unroll
        for (int n = 0; n < 4; ++n) acc[m][n] = (f32x4){0.f, 0.f, 0.f, 0.f};

    // prologue: buf0 <- tile0 (4 regions), buf1 <- tile1 (Bk0,Ak0,Bk1)
    stage_region(smem, 32768,         gB, 0, 0, tid);
    stage_region(smem, 0,             gA, 0, 0, tid);
    stage_region(smem, 49152,         gB, 0, 1, tid);
    stage_region(smem, 16384,         gA, 0, 1, tid);
    stage_region(smem, 65536 + 32768, gB, 1, 0, tid);
    stage_region(smem, 65536 + 0,     gA, 1, 0, tid);
    stage_region(smem, 65536 + 49152, gB, 1, 1, tid);
    asm volatile("s_waitcnt vmcnt(6)" ::: "memory");
    __builtin_amdgcn_sched_barrier(0);
    __builtin_amdgcn_s_barrier();

    bf16x8 bf[4];

#pragma unroll 1
    for (int i = 0; i < 16; ++i) {
        const int t1b = 2 * i + 1;
        const int t2  = (2 * i + 2 < 32) ? 2 * i + 2 : 31;   // clamp: idempotent tail
        const int t3  = (2 * i + 3 < 32) ? 2 * i + 3 : 31;

        PHASE(0, 0, 0, true,  stage_region(smem, 65536 + 16384, gA, t1b, 1, tid), false)
        PHASE(0, 4, 0, false, stage_region(smem, 32768,         gB, t2,  0, tid), false)
        PHASE(0, 0, 1, true,  stage_region(smem, 0,             gA, t2,  0, tid), false)
        PHASE(0, 4, 1, false, stage_region(smem, 49152,         gB, t2,  1, tid), true)
        PHASE(1, 0, 0, true,  stage_region(smem, 16384,         gA, t2,  1, tid), false)
        PHASE(1, 4, 0, false, stage_region(smem, 65536 + 32768, gB, t3,  0, tid), false)
        PHASE(1, 0, 1, true,  stage_region(smem, 65536 + 0,     gA, t3,  0, tid), false)
        PHASE(1, 4, 1, false, stage_region(smem, 65536 + 49152, gB, t3,  1, tid), true)
    }

    if (FUSED) {
        // softmax stage 1 (store only): e = exp(logit), fp16.
        unsigned short* ep = expw + (size_t)(i0 + wr128) * V + n0 + wc64;
#pragma unroll
        for (int m = 0; m < 8; ++m) {
#pragma unroll
            for (int r = 0; r < 4; ++r) {
                unsigned short* p = ep + (size_t)(m * 16 + lq * 4 + r) * V;
#pragma unroll
                for (int n = 0; n < 4; ++n)
                    p[n * 16 + lr] = f2h(__expf(acc[m][n][r]));
            }
        }
    } else {
        float* op = out + (size_t)(i0 + wr128) * V + n0 + wc64;
#pragma unroll
        for (int m = 0; m < 8; ++m)
#pragma unroll
            for (int n = 0; n < 4; ++n)
#pragma unroll
                for (int r = 0; r < 4; ++r)
                    op[(size_t)(m * 16 + lq * 4 + r) * V + n * 16 + lr] = acc[m][n][r];
    }
}

// ---- softmax stage 2: single pass — sum fp16 exp row, scale, write fp32 ----
__global__ __launch_bounds__(256) void normalize_kernel(const unsigned short* __restrict__ expw,
                                                        float* __restrict__ out) {
    const int row  = blockIdx.x * 4 + (threadIdx.x >> 6);
    const int lane = threadIdx.x & 63;

    const unsigned short* ip = expw + (size_t)row * V;
    float* op = out + (size_t)row * V;

    float v[32];
    float sum = 0.0f;
#pragma unroll
    for (int t = 0; t < 4; ++t) {
        const int base = (t * 64 + lane) * 8;
        ushort4 u0 = *(const ushort4*)(ip + base);
        ushort4 u1 = *(const ushort4*)(ip + base + 4);
        v[t * 8 + 0] = h2f(u0.x); v[t * 8 + 1] = h2f(u0.y);
        v[t * 8 + 2] = h2f(u0.z); v[t * 8 + 3] = h2f(u0.w);
        v[t * 8 + 4] = h2f(u1.x); v[t * 8 + 5] = h2f(u1.y);
        v[t * 8 + 6] = h2f(u1.z); v[t * 8 + 7] = h2f(u1.w);
#pragma unroll
        for (int k = 0; k < 8; ++k) sum += v[t * 8 + k];
    }
#pragma unroll
    for (int o = 32; o; o >>= 1) sum += __shfl_xor(sum, o);
    const float inv = 1.0f / sum;

#pragma unroll
    for (int t = 0; t < 4; ++t) {
        const int base = (t * 64 + lane) * 8;
        float4 o0, o1;
        o0.x = v[t * 8 + 0] * inv; o0.y = v[t * 8 + 1] * inv;
        o0.z = v[t * 8 + 2] * inv; o0.w = v[t * 8 + 3] * inv;
        o1.x = v[t * 8 + 4] * inv; o1.y = v[t * 8 + 5] * inv;
        o1.z = v[t * 8 + 6] * inv; o1.w = v[t * 8 + 7] * inv;
        *(float4*)(op + base)     = o0;
        *(float4*)(op + base + 4) = o1;
    }
}

// ---- backup MFMA GEMM (proven round-3 kernel) ----
__global__ __launch_bounds__(256) void gemm_mfma(const unsigned short* __restrict__ adjb,
                                                 const unsigned short* __restrict__ wtb,
                                                 float* __restrict__ out) {
    const int bid = blockIdx.x;
    const int swz = (bid & 7) * 256 + (bid >> 3);
    const int by = swz >> 4;
    const int bx = swz & 15;
    const int i0 = by * 128;
    const int n0 = bx * 128;

    __shared__ alignas(16) unsigned short As[128 * 32];
    __shared__ alignas(16) unsigned short Bs[128 * 32];

    const int tid  = threadIdx.x;
    const int wid  = tid >> 6;
    const int lane = tid & 63;
    const int wr = wid >> 1, wc = wid & 1;
    const int lr = lane & 15, lq = lane >> 4;

    f32x4 acc[4][4];
#pragma unroll
    for (int m = 0; m < 4; ++m)
#pragma unroll
        for (int n = 0; n < 4; ++n) acc[m][n] = (f32x4){0.f, 0.f, 0.f, 0.f};

    const unsigned short* ga = adjb + (size_t)(i0 + (tid >> 2)) * V + (tid & 3) * 8;
    const unsigned short* gb = wtb  + (size_t)(n0 + (tid >> 2)) * V + (tid & 3) * 8;
    unsigned short* lA = &As[tid * 8];
    unsigned short* lB = &Bs[tid * 8];
    const size_t rowskip = (size_t)64 * V;

    for (int kt = 0; kt < 64; ++kt) {
        const int k0 = kt * 32;
        if (kt) __syncthreads();
        GLOAD_LDS16(ga + k0,           lA);
        GLOAD_LDS16(ga + rowskip + k0, lA + 256 * 8);
        GLOAD_LDS16(gb + k0,           lB);
        GLOAD_LDS16(gb + rowskip + k0, lB + 256 * 8);
        __syncthreads();

        bf16x8 a[4], b[4];
#pragma unroll
        for (int m = 0; m < 4; ++m)
            a[m] = *(const bf16x8*)&As[(wr * 64 + m * 16 + lr) * 32 + lq * 8];
#pragma unroll
        for (int n = 0; n < 4; ++n)
            b[n] = *(const bf16x8*)&Bs[(wc * 64 + n * 16 + lr) * 32 + lq * 8];
#pragma unroll
        for (int m = 0; m < 4; ++m)
#pragma unroll
            for (int n = 0; n < 4; ++n)
                acc[m][n] = __builtin_amdgcn_mfma_f32_16x16x32_bf16(a[m], b[n], acc[m][n], 0, 0, 0);
    }

    float* outp = out + (size_t)(i0 + wr * 64) * V + n0 + wc * 64;
#pragma unroll
    for (int m = 0; m < 4; ++m) {
        const int r0 = m * 16 + lq * 4;
#pragma unroll
        for (int n = 0; n < 4; ++n) {
            const int cc = n * 16 + lr;
#pragma unroll
            for (int r = 0; r < 4; ++r)
                outp[(size_t)(r0 + r) * V + cc] = acc[m][n][r];
        }
    }
}

// ============================ FALLBACK PATH (fp32, no ws) ============================

__global__ __launch_bounds__(256) void adj_kernel(const float* __restrict__ x,
                                                  float* __restrict__ adj) {
    const int n  = blockIdx.z;
    const int i0 = blockIdx.y * 64;
    const int j0 = blockIdx.x * 64;

    __shared__ float Xi[64][65];
    __shared__ float Xj[64][65];

    const float* xn = x + (size_t)n * V * C;
    const int tid = threadIdx.x;
    const int lr = tid >> 4;
    const int lc = (tid & 15) << 2;
#pragma unroll
    for (int it = 0; it < 4; ++it) {
        const int r = lr + it * 16;
        float4 vi = *(const float4*)(xn + (size_t)(i0 + r) * C + lc);
        float4 vj = *(const float4*)(xn + (size_t)(j0 + r) * C + lc);
        Xi[r][lc + 0] = vi.x; Xi[r][lc + 1] = vi.y; Xi[r][lc + 2] = vi.z; Xi[r][lc + 3] = vi.w;
        Xj[r][lc + 0] = vj.x; Xj[r][lc + 1] = vj.y; Xj[r][lc + 2] = vj.z; Xj[r][lc + 3] = vj.w;
    }
    __syncthreads();

    const int ti = (tid >> 4) << 2;
    const int tj = (tid & 15) << 2;

    float acc[4][4] = {};
#pragma unroll 4
    for (int c = 0; c < C; ++c) {
        float ai[4], bj[4];
#pragma unroll
        for (int a = 0; a < 4; ++a) ai[a] = Xi[ti + a][c];
#pragma unroll
        for (int b = 0; b < 4; ++b) bj[b] = Xj[tj + b][c];
#pragma unroll
        for (int a = 0; a < 4; ++a)
#pragma unroll
            for (int b = 0; b < 4; ++b) {
                const float d = ai[a] - bj[b];
                acc[a][b] = fmaf(d, d, acc[a][b]);
            }
    }

    float* outb = adj + ((size_t)n * V + i0) * V + j0;
#pragma unroll
    for (int a = 0; a < 4; ++a) {
        float4 o0;
        o0.x = expf(-0.5f * sqrtf(acc[a][0]));
        o0.y = expf(-0.5f * sqrtf(acc[a][1]));
        o0.z = expf(-0.5f * sqrtf(acc[a][2]));
        o0.w = expf(-0.5f * sqrtf(acc[a][3]));
        *(float4*)(outb + (size_t)(ti + a) * V + tj) = o0;
    }
}

__global__ __launch_bounds__(256) void gemm_inplace(float* __restrict__ adjout,
                                                    const float* __restrict__ w) {
    const int n  = blockIdx.y;
    const int i0 = blockIdx.x * 8;

    __shared__ float rows[8][V];

    float* base = adjout + ((size_t)n * V + i0) * V;
    const int tid = threadIdx.x;

    for (int t = tid; t < (8 * V) / 4; t += 256) {
        const int r = t >> 9;
        const int c = (t & 511) << 2;
        float4 v = *(const float4*)(base + (size_t)r * V + c);
        rows[r][c + 0] = v.x; rows[r][c + 1] = v.y; rows[r][c + 2] = v.z; rows[r][c + 3] = v.w;
    }
    __syncthreads();

    float acc[8][8] = {};
    const int k0 = tid << 3;
    const float* wp = w + k0;

    for (int j = 0; j < V; ++j) {
        float a[8];
#pragma unroll
        for (int r = 0; r < 8; ++r) a[r] = rows[r][j];
        const float* wr = wp + (size_t)j * V;
        const float4 w0 = *(const float4*)(wr);
        const float4 w1 = *(const float4*)(wr + 4);
        const float wv[8] = {w0.x, w0.y, w0.z, w0.w, w1.x, w1.y, w1.z, w1.w};
#pragma unroll
        for (int r = 0; r < 8; ++r)
#pragma unroll
            for (int c = 0; c < 8; ++c)
                acc[r][c] = fmaf(a[r], wv[c], acc[r][c]);
    }

#pragma unroll
    for (int r = 0; r < 8; ++r) {
        float4 o0, o1;
        o0.x = acc[r][0]; o0.y = acc[r][1]; o0.z = acc[r][2]; o0.w = acc[r][3];
        o1.x = acc[r][4]; o1.y = acc[r][5]; o1.z = acc[r][6]; o1.w = acc[r][7];
        *(float4*)(base + (size_t)r * V + k0)     = o0;
        *(float4*)(base + (size_t)r * V + k0 + 4) = o1;
    }
}

// ---------------- in-place row softmax (mid-tier + fallback paths) ----------------
__global__ __launch_bounds__(256) void softmax_kernel(float* __restrict__ out) {
    const int row  = blockIdx.x * 4 + (threadIdx.x >> 6);
    const int lane = threadIdx.x & 63;
    float* p = out + (size_t)row * V;

    float4 v[8];
#pragma unroll
    for (int s = 0; s < 8; ++s)
        v[s] = *(const float4*)(p + (size_t)(s * 64 + lane) * 4);

    float m = -INFINITY;
#pragma unroll
    for (int s = 0; s < 8; ++s)
        m = fmaxf(m, fmaxf(fmaxf(v[s].x, v[s].y), fmaxf(v[s].z, v[s].w)));
#pragma unroll
    for (int o = 32; o; o >>= 1) m = fmaxf(m, __shfl_xor(m, o));

    float sum = 0.0f;
#pragma unroll
    for (int s = 0; s < 8; ++s) {
        v[s].x = expf(v[s].x - m);
        v[s].y = expf(v[s].y - m);
        v[s].z = expf(v[s].z - m);
        v[s].w = expf(v[s].w - m);
        sum += (v[s].x + v[s].y) + (v[s].z + v[s].w);
    }
#pragma unroll
    for (int o = 32; o; o >>= 1) sum += __shfl_xor(sum, o);

    const float inv = 1.0f / sum;
#pragma unroll
    for (int s = 0; s < 8; ++s) {
        float4 o4;
        o4.x = v[s].x * inv; o4.y = v[s].y * inv;
        o4.z = v[s].z * inv; o4.w = v[s].w * inv;
        *(float4*)(p + (size_t)(s * 64 + lane) * 4) = o4;
    }
}

extern "C" void kernel_launch(void* const* d_in, const int* in_sizes, int n_in,
                              void* d_out, int out_size, void* d_ws, size_t ws_size,
                              hipStream_t stream) {
    const float* x = (const float*)d_in[0];
    const float* w = (const float*)d_in[1];
    float* out = (float*)d_out;

    const size_t adj_elems = (size_t)M_TOTAL * V;                  // 33.5M
    const size_t wt_elems  = (size_t)V * V;                        // 4.2M
    const size_t need      = (adj_elems + wt_elems) * 2;           // 75,497,472 B
    const size_t exp_off   = need;                                 // bytes
    const size_t need_big  = exp_off + adj_elems * 2;              // 142,606,336 B

    if (ws_size >= need) {
        unsigned short* adjb = (unsigned short*)d_ws;
        unsigned short* wtb  = adjb + adj_elems;

        adj_mfma<<<dim3(V / 128, V / 128, NB), 256, 0, stream>>>(x, adjb);
        wt_kernel<<<dim3(V / 64, V / 64), 256, 0, stream>>>(w, wtb);

        if (ws_size >= need_big) {
            unsigned short* expw = (unsigned short*)((char*)d_ws + exp_off);
            hipError_t ok = hipFuncSetAttribute(
                reinterpret_cast<const void*>(&gemm_8ph<1>),
                hipFuncAttributeMaxDynamicSharedMemorySize, 131072);
            if (ok == hipSuccess) {
                gemm_8ph<1><<<512, 512, 131072, stream>>>(adjb, wtb, out, expw);
                normalize_kernel<<<M_TOTAL / 4, 256, 0, stream>>>(expw, out);
                return;
            }
        }
        hipError_t ok = hipFuncSetAttribute(
            reinterpret_cast<const void*>(&gemm_8ph<0>),
            hipFuncAttributeMaxDynamicSharedMemorySize, 131072);
        if (ok == hipSuccess) {
            gemm_8ph<0><<<512, 512, 131072, stream>>>(adjb, wtb, out, nullptr);
        } else {
            gemm_mfma<<<2048, 256, 0, stream>>>(adjb, wtb, out);
        }
        softmax_kernel<<<(NB * V) / 4, 256, 0, stream>>>(out);
    } else {
        dim3 g1(V / 64, V / 64, NB);
        adj_kernel<<<g1, 256, 0, stream>>>(x, out);
        dim3 g2(V / 8, NB);
        gemm_inplace<<<g2, 256, 0, stream>>>(out, w);
        softmax_kernel<<<(NB * V) / 4, 256, 0, stream>>>(out);
    }
}